// Round 13
// baseline (389.584 us; speedup 1.0000x reference)
//
#include <hip/hip_runtime.h>
#include <hip/hip_fp16.h>

#define NFEAT 128

typedef _Float16 v8hf __attribute__((ext_vector_type(8)));
typedef float v4f __attribute__((ext_vector_type(4)));

// ------- degree histogram + per-edge rank (incl. self edges) + W prep --------
__global__ void k_deg_rank_w(const int* __restrict__ dst, int* __restrict__ deg,
                             int* __restrict__ rank, int E, int N,
                             const float* __restrict__ W1, const float* __restrict__ W2,
                             _Float16* __restrict__ Wt1, _Float16* __restrict__ Wt2) {
  int e = blockIdx.x * blockDim.x + threadIdx.x;
  if (e < E) rank[e] = atomicAdd(&deg[dst[e]], 1);
  else if (e < E + N) rank[e] = atomicAdd(&deg[e - E], 1);
  else if (e < E + N + 32768) {
    int idx = e - E - N;             // 0..32767
    const float* W = (idx < 16384) ? W1 : W2;
    _Float16* Wt = (idx < 16384) ? Wt1 : Wt2;
    int i = idx & 16383;
    int k = i >> 7, n = i & 127;
    Wt[n * 128 + k] = (_Float16)W[k * 128 + n];
  }
}

// ---------------- 2-level exclusive scan over degrees ------------------------
__global__ __launch_bounds__(1024) void k_scan_blocks(const int* __restrict__ deg,
    int* __restrict__ base, int* __restrict__ partials, int n) {
  __shared__ int buf[1024];
  int tid = threadIdx.x;
  int i = blockIdx.x * 1024 + tid;
  int v = (i < n) ? deg[i] : 0;
  buf[tid] = v;
  __syncthreads();
  #pragma unroll
  for (int off = 1; off < 1024; off <<= 1) {
    int t = (tid >= off) ? buf[tid - off] : 0;
    __syncthreads();
    buf[tid] += t;
    __syncthreads();
  }
  if (i <= n) base[i] = buf[tid] - v;
  if (tid == 1023) partials[blockIdx.x] = buf[tid];
}

__global__ void k_scan_partials(int* __restrict__ partials, int nb) {
  __shared__ int buf[128];
  int tid = threadIdx.x;
  int v = (tid < nb) ? partials[tid] : 0;
  buf[tid] = v;
  __syncthreads();
  #pragma unroll
  for (int off = 1; off < 128; off <<= 1) {
    int t = (tid >= off) ? buf[tid - off] : 0;
    __syncthreads();
    buf[tid] += t;
    __syncthreads();
  }
  if (tid < nb) partials[tid] = buf[tid] - v;
}

__global__ void k_finalize_base(int* __restrict__ base, const int* __restrict__ partials,
    const int* __restrict__ deg, float* __restrict__ dinv, int n) {
  int i = blockIdx.x * blockDim.x + threadIdx.x;
  if (i <= n) {
    base[i] += partials[i >> 10];
    if (i < n) dinv[i] = rsqrtf((float)deg[i]);   // deg already includes self
  }
}

__global__ void k_scatter(const int* __restrict__ src, const int* __restrict__ dst,
    const int* __restrict__ rank, const int* __restrict__ base,
    int* __restrict__ ssrc, int E, int N) {
  int e = blockIdx.x * blockDim.x + threadIdx.x;
  if (e < E) ssrc[base[dst[e]] + rank[e]] = src[e];
  else if (e < E + N) { int n = e - E; ssrc[base[n] + rank[e]] = n; }
}

// ------- persistent MFMA fp16 GEMM: g16[r][:] = half((A[r][:]@W)*dinv[r]) ----
// Grid = fixed block count; Wt staged into LDS ONCE per block, then the block
// grid-strides over 64-row chunks (stage A -> MFMA -> store). Saves ~3x Wt
// restaging + per-block cold start vs one-chunk-per-block.
template <typename AT>
__global__ __launch_bounds__(256) void k_gemm_mfma(
    const AT* __restrict__ A, const _Float16* __restrict__ Wt,
    const float* __restrict__ dinv, _Float16* __restrict__ g16, int N,
    int nChunks) {
  __shared__ _Float16 As[64][136];
  __shared__ _Float16 Ws[128][136];
  const int tid = threadIdx.x;

  if (blockIdx.x == 0 && tid < 16) {   // zero sentinel row N
    v8hf z;
    #pragma unroll
    for (int j = 0; j < 8; j++) z[j] = (_Float16)0.f;
    *(v8hf*)(g16 + (size_t)N * NFEAT + tid * 8) = z;
  }

  #pragma unroll
  for (int i = 0; i < 8; i++) {       // Wt: once per block
    int idx = tid + i * 256;
    int row = idx >> 4;
    int c8 = idx & 15;
    *(uint4*)&Ws[row][c8 * 8] = *(const uint4*)(Wt + (size_t)row * 128 + c8 * 8);
  }

  const int wv = tid >> 6;
  const int lane = tid & 63;
  const int m = lane & 15;
  const int q = lane >> 4;

  for (int chunk = blockIdx.x; chunk < nChunks; chunk += gridDim.x) {
    const int row0 = chunk * 64;
    __syncthreads();                  // prev chunk's As reads done / Ws ready

    if constexpr (sizeof(AT) == 4) {  // fp32 input: load + cast
      #pragma unroll
      for (int i = 0; i < 8; i++) {
        int idx = tid + i * 256;      // 0..2047
        int row = idx >> 5;
        int c4 = idx & 31;
        int gr = row0 + row; gr = (gr < N) ? gr : (N - 1);
        float4 v = *(const float4*)((const float*)A + (size_t)gr * NFEAT + c4 * 4);
        _Float16* p = &As[row][c4 * 4];
        p[0] = (_Float16)v.x; p[1] = (_Float16)v.y;
        p[2] = (_Float16)v.z; p[3] = (_Float16)v.w;
      }
    } else {                          // fp16 input: straight copy
      #pragma unroll
      for (int i = 0; i < 4; i++) {
        int idx = tid + i * 256;
        int row = idx >> 4;
        int c8 = idx & 15;
        int gr = row0 + row; gr = (gr < N) ? gr : (N - 1);
        *(uint4*)&As[row][c8 * 8] =
            *(const uint4*)((const _Float16*)A + (size_t)gr * NFEAT + c8 * 8);
      }
    }
    __syncthreads();

    v4f acc[8] = {};
    const _Float16* arow = &As[wv * 16 + m][0];
    #pragma unroll
    for (int kt = 0; kt < 4; kt++) {
      v8hf af = *(const v8hf*)(arow + kt * 32 + q * 8);
      #pragma unroll
      for (int ct = 0; ct < 8; ct++) {
        v8hf bf = *(const v8hf*)(&Ws[ct * 16 + m][kt * 32 + q * 8]);
        acc[ct] = __builtin_amdgcn_mfma_f32_16x16x32_f16(af, bf, acc[ct], 0, 0, 0);
      }
    }

    int nd[4]; float dv[4];
    #pragma unroll
    for (int r = 0; r < 4; r++) {
      nd[r] = row0 + wv * 16 + q * 4 + r;
      int c = (nd[r] < N) ? nd[r] : (N - 1);
      dv[r] = dinv[c];
    }
    #pragma unroll
    for (int ct = 0; ct < 8; ct++)
      #pragma unroll
      for (int r = 0; r < 4; r++)
        if (nd[r] < N)
          g16[(size_t)nd[r] * NFEAT + ct * 16 + m] = (_Float16)(acc[ct][r] * dv[r]);
  }
}

// ---------------- agg: wave per node, depth-2 pipelined gathers --------------
__global__ __launch_bounds__(256) void k_agg(
    const _Float16* __restrict__ g, const float* __restrict__ dinv,
    const int* __restrict__ base, const int* __restrict__ ssrc,
    const float* __restrict__ bias, _Float16* __restrict__ hB, int N) {
  const int lane = threadIdx.x & 63;
  const int n = blockIdx.x * 4 + (threadIdx.x >> 6);
  if (n >= N) return;
  const int gq = lane >> 4;
  const int l = lane & 15;
  const int b0 = base[n], b1 = base[n + 1];

  int e = b0;
  int p0 = e + gq, p1 = e + 4 + gq;
  int i0 = ssrc[p0], i1 = ssrc[p1];          // +8 slack makes loads safe
  i0 = (p0 < b1) ? i0 : N;
  i1 = (p1 < b1) ? i1 : N;
  v8hf r0 = *(const v8hf*)(g + (size_t)i0 * NFEAT + l * 8);
  v8hf r1 = *(const v8hf*)(g + (size_t)i1 * NFEAT + l * 8);
  int e2 = e + 8;
  int j0 = N, j1 = N;
  if (e2 < b1) {
    int q0 = e2 + gq, q1 = e2 + 4 + gq;
    j0 = ssrc[q0]; j1 = ssrc[q1];
    j0 = (q0 < b1) ? j0 : N;
    j1 = (q1 < b1) ? j1 : N;
  }

  float acc[8] = {};
  while (true) {
    bool more = (e2 < b1);
    v8hf s0, s1;
    if (more) {
      s0 = *(const v8hf*)(g + (size_t)j0 * NFEAT + l * 8);
      s1 = *(const v8hf*)(g + (size_t)j1 * NFEAT + l * 8);
    }
    int e3 = e2 + 8;
    int c0 = N, c1 = N;
    if (e3 < b1) {
      int q0 = e3 + gq, q1 = e3 + 4 + gq;
      c0 = ssrc[q0]; c1 = ssrc[q1];
      c0 = (q0 < b1) ? c0 : N;
      c1 = (q1 < b1) ? c1 : N;
    }
    #pragma unroll
    for (int j = 0; j < 8; j++) acc[j] += (float)r0[j] + (float)r1[j];
    if (!more) break;
    r0 = s0; r1 = s1;
    j0 = c0; j1 = c1;
    e2 = e3;
  }

  #pragma unroll
  for (int j = 0; j < 8; j++) {
    acc[j] += __shfl_xor(acc[j], 16, 64);
    acc[j] += __shfl_xor(acc[j], 32, 64);
  }
  if (gq == 0) {
    float dvn = dinv[n];
    const float* bp = bias + l * 8;
    float4 bb0 = *(const float4*)(bp);
    float4 bb1 = *(const float4*)(bp + 4);
    float bv[8] = {bb0.x, bb0.y, bb0.z, bb0.w, bb1.x, bb1.y, bb1.z, bb1.w};
    v8hf o;
    #pragma unroll
    for (int j = 0; j < 8; j++)
      o[j] = (_Float16)fmaxf(acc[j] * dvn + bv[j], 0.f);
    *(v8hf*)(hB + (size_t)n * NFEAT + l * 8) = o;
  }
}

// ---------------- layer-2 agg fused with final linear (same pipeline) --------
__global__ __launch_bounds__(256) void k_agg_final(
    const _Float16* __restrict__ g, const float* __restrict__ dinv,
    const int* __restrict__ base, const int* __restrict__ ssrc,
    const float* __restrict__ bias, const float* __restrict__ wlin,
    const float* __restrict__ blin, float* __restrict__ out, int N) {
  const int lane = threadIdx.x & 63;
  const int n = blockIdx.x * 4 + (threadIdx.x >> 6);
  if (n >= N) return;
  const int gq = lane >> 4;
  const int l = lane & 15;
  const int b0 = base[n], b1 = base[n + 1];

  int e = b0;
  int p0 = e + gq, p1 = e + 4 + gq;
  int i0 = ssrc[p0], i1 = ssrc[p1];
  i0 = (p0 < b1) ? i0 : N;
  i1 = (p1 < b1) ? i1 : N;
  v8hf r0 = *(const v8hf*)(g + (size_t)i0 * NFEAT + l * 8);
  v8hf r1 = *(const v8hf*)(g + (size_t)i1 * NFEAT + l * 8);
  int e2 = e + 8;
  int j0 = N, j1 = N;
  if (e2 < b1) {
    int q0 = e2 + gq, q1 = e2 + 4 + gq;
    j0 = ssrc[q0]; j1 = ssrc[q1];
    j0 = (q0 < b1) ? j0 : N;
    j1 = (q1 < b1) ? j1 : N;
  }

  float acc[8] = {};
  while (true) {
    bool more = (e2 < b1);
    v8hf s0, s1;
    if (more) {
      s0 = *(const v8hf*)(g + (size_t)j0 * NFEAT + l * 8);
      s1 = *(const v8hf*)(g + (size_t)j1 * NFEAT + l * 8);
    }
    int e3 = e2 + 8;
    int c0 = N, c1 = N;
    if (e3 < b1) {
      int q0 = e3 + gq, q1 = e3 + 4 + gq;
      c0 = ssrc[q0]; c1 = ssrc[q1];
      c0 = (q0 < b1) ? c0 : N;
      c1 = (q1 < b1) ? c1 : N;
    }
    #pragma unroll
    for (int j = 0; j < 8; j++) acc[j] += (float)r0[j] + (float)r1[j];
    if (!more) break;
    r0 = s0; r1 = s1;
    j0 = c0; j1 = c1;
    e2 = e3;
  }

  #pragma unroll
  for (int j = 0; j < 8; j++) {
    acc[j] += __shfl_xor(acc[j], 16, 64);
    acc[j] += __shfl_xor(acc[j], 32, 64);
  }
  float dvn = dinv[n];
  const float* bp = bias + l * 8;
  const float* wp = wlin + l * 8;
  float4 bb0 = *(const float4*)(bp);
  float4 bb1 = *(const float4*)(bp + 4);
  float4 wl0 = *(const float4*)(wp);
  float4 wl1 = *(const float4*)(wp + 4);
  float bv[8] = {bb0.x, bb0.y, bb0.z, bb0.w, bb1.x, bb1.y, bb1.z, bb1.w};
  float wv[8] = {wl0.x, wl0.y, wl0.z, wl0.w, wl1.x, wl1.y, wl1.z, wl1.w};
  float pv = 0.f;
  #pragma unroll
  for (int j = 0; j < 8; j++)
    pv += fmaxf(acc[j] * dvn + bv[j], 0.f) * wv[j];
  pv += __shfl_xor(pv, 1, 64);
  pv += __shfl_xor(pv, 2, 64);
  pv += __shfl_xor(pv, 4, 64);
  pv += __shfl_xor(pv, 8, 64);
  if (lane == 0) out[n] = pv + blin[0];
}

extern "C" void kernel_launch(void* const* d_in, const int* in_sizes, int n_in,
                              void* d_out, int out_size, void* d_ws, size_t ws_size,
                              hipStream_t stream) {
  const float* x    = (const float*)d_in[0];
  const int*   ei   = (const int*)d_in[1];
  const float* W1   = (const float*)d_in[2];
  const float* b1   = (const float*)d_in[3];
  const float* W2   = (const float*)d_in[4];
  const float* b2   = (const float*)d_in[5];
  const float* Wlin = (const float*)d_in[6];
  const float* blin = (const float*)d_in[7];
  const int N = in_sizes[0] / NFEAT;
  const int E = in_sizes[1] / 2;
  const int* src = ei;
  const int* dst = ei + E;
  const int Etot = E + N;   // real edges + self edges

  // workspace layout (4B units)
  int* ws_i = (int*)d_ws;
  size_t off = 0;
  int* deg      = ws_i + off; off += N;
  int* base     = ws_i + off; off += (size_t)N + 1;
  off = (off + 3) & ~(size_t)3;
  int* partials = ws_i + off; off += 128;
  int* ssrc     = ws_i + off; off += Etot + 8;   // +8 slack for tail loads
  float* dinv   = (float*)(ws_i + off); off += N;
  off = (off + 3) & ~(size_t)3;
  _Float16* Wt1 = (_Float16*)(ws_i + off); off += 8192;
  _Float16* Wt2 = (_Float16*)(ws_i + off); off += 8192;
  _Float16* g16 = (_Float16*)(ws_i + off); off += (size_t)(N + 1) * 64;  // +sentinel
  _Float16* hB  = (_Float16*)(ws_i + off); off += (size_t)N * 64;
  int* rank     = (int*)g16;   // Etot ints, consumed by k_scatter before g16 written

  hipMemsetAsync(deg, 0, (size_t)N * sizeof(int), stream);

  const int tpbE = 256;
  const int gE = (Etot + 32768 + tpbE - 1) / tpbE;
  k_deg_rank_w<<<gE, tpbE, 0, stream>>>(dst, deg, rank, E, N, W1, W2, Wt1, Wt2);

  const int nb = (N + 1 + 1023) / 1024;
  k_scan_blocks<<<nb, 1024, 0, stream>>>(deg, base, partials, N);
  k_scan_partials<<<1, 128, 0, stream>>>(partials, nb);
  k_finalize_base<<<((N + 1) + 255) / 256, 256, 0, stream>>>(base, partials, deg, dinv, N);
  k_scatter<<<(Etot + tpbE - 1) / tpbE, tpbE, 0, stream>>>(src, dst, rank, base, ssrc, E, N);

  const int nChunks = (N + 63) / 64;
  const int gg = 512;                // persistent blocks; each loops ~3 chunks
  const int ga = (N + 3) / 4;
  // layer 1
  k_gemm_mfma<float><<<gg, 256, 0, stream>>>(x, Wt1, dinv, g16, N, nChunks);
  k_agg<<<ga, 256, 0, stream>>>(g16, dinv, base, ssrc, b1, hB, N);
  // layer 2 + fused final linear
  k_gemm_mfma<_Float16><<<gg, 256, 0, stream>>>(hB, Wt2, dinv, g16, N, nChunks);
  k_agg_final<<<ga, 256, 0, stream>>>(g16, dinv, base, ssrc, b2,
                                      Wlin, blin, (float*)d_out, N);
}